// Round 1
// baseline (914.953 us; speedup 1.0000x reference)
//
#include <hip/hip_runtime.h>
#include <stdint.h>
#include <stddef.h>

// ---------- types ----------
typedef _Float16 half_t;
typedef half_t half8  __attribute__((ext_vector_type(8)));
typedef half_t half4v __attribute__((ext_vector_type(4)));
typedef float  f32x4  __attribute__((ext_vector_type(4)));

__device__ __forceinline__ float fast_sigmoid(float x) {
    float e = __builtin_amdgcn_exp2f(-1.44269504f * x);
    return __builtin_amdgcn_rcpf(1.0f + e);
}
__device__ __forceinline__ float fast_tanh(float x) {
    // tanh(x) = 1 - 2/(exp(2x)+1)
    float e = __builtin_amdgcn_exp2f(2.88539008f * x);
    return 1.0f - 2.0f * __builtin_amdgcn_rcpf(1.0f + e);
}

// ---------------------------------------------------------------------------
// Prep: reorder W [1024][256] f32 (row-major) into MFMA-B fragment order, f16.
// For j-tile T=j/16 (64), k-tile kt=k/32 (8), lane l (64): 8 halves at
// ((T*8+kt)*64 + l)*8 :
//   elems 0..3 : k = kt*32 +      (l>>4)*4 + e ,  j = T*16 + (l&15)
//   elems 4..7 : k = kt*32 + 16 + (l>>4)*4 + e
// The same (lane-group,reg)->k bijection is used when loading A from LDS, so
// the MFMA result is correct independent of the HW's internal k ordering
// (A and B operand layouts are mirrored on CDNA).
// ---------------------------------------------------------------------------
__global__ __launch_bounds__(64) void shuffle_w_kernel(
    const float* __restrict__ W, half_t* __restrict__ out)
{
    const int blk = blockIdx.x;         // 512 = 64 T * 8 kt
    const int T = blk >> 3, kt = blk & 7;
    const int l = threadIdx.x;
    const int j  = T * 16 + (l & 15);
    const int kb = kt * 32 + ((l >> 4) << 2);
    half8 v;
#pragma unroll
    for (int h = 0; h < 2; ++h)
#pragma unroll
        for (int e = 0; e < 4; ++e)
            v[h * 4 + e] = (half_t)W[j * 256 + kb + h * 16 + e];
    *reinterpret_cast<half8*>(out + (size_t)(blk * 64 + l) * 8) = v;
}

// ---------------------------------------------------------------------------
// One K=256 GEMM accumulation: acc[mt*8+n] += hx_tile(64x256) @ W^T columns.
// A from LDS (swizzled rows), B from pre-shuffled global (L2-resident).
// ---------------------------------------------------------------------------
__device__ __forceinline__ void gemm_ktile(
    f32x4* acc, const half_t* __restrict__ lhx,
    const half_t* __restrict__ Ws, const int* Tn,
    int lm, int lg, int l)
{
#pragma unroll
    for (int kt = 0; kt < 8; ++kt) {
        half8 a[4];
#pragma unroll
        for (int mt = 0; mt < 4; ++mt) {
            const int p   = mt * 16 + lm;
            const int swz = (p & 7) << 2;           // XOR-swizzle in half-units
            const int k0  = kt * 32 + lg * 4;
            union { half8 v; half4v h[2]; } t;
            t.h[0] = *reinterpret_cast<const half4v*>(&lhx[p * 256 + ((k0     ) ^ swz)]);
            t.h[1] = *reinterpret_cast<const half4v*>(&lhx[p * 256 + ((k0 + 16) ^ swz)]);
            a[mt] = t.v;
        }
#pragma unroll
        for (int n = 0; n < 8; ++n) {
            half8 bb = *reinterpret_cast<const half8*>(
                &Ws[(size_t)((Tn[n] * 8 + kt) * 64 + l) * 8]);
#pragma unroll
            for (int mt = 0; mt < 4; ++mt)
                acc[mt * 8 + n] = __builtin_amdgcn_mfma_f32_16x16x32_f16(
                    a[mt], bb, acc[mt * 8 + n], 0, 0, 0);
        }
    }
}

// ---------------------------------------------------------------------------
// Persistent LSTM: each block owns 64 rows for all 16 steps.
//   phase 0: x_proj = x_tile @ W_ih^T + b_ih + b_hh  -> LDS (f16 frag dump)
//   steps  : gates = x_proj + hx @ W_hh^T ; LSTM update ; head -> out
// LDS: hx 64*256 f16 = 32 KB (XOR-swizzled rows), x_proj frag dump = 128 KB.
// ---------------------------------------------------------------------------
__global__ __launch_bounds__(512, 2) void lstm_kernel(
    const float* __restrict__ x,      // [8][256][1600]
    const float* __restrict__ hx0,    // [12800][256]
    const float* __restrict__ cx0,    // [12800][256]
    const float* __restrict__ b_ih,   // [1024]
    const float* __restrict__ b_hh,   // [1024]
    const float* __restrict__ W_lin,  // [2][256]
    const float* __restrict__ b_lin,  // [2]
    const half_t* __restrict__ Wih_s, // shuffled f16
    const half_t* __restrict__ Whh_s, // shuffled f16
    float* __restrict__ out)          // [12800][16][2]
{
    __shared__ __align__(16) half_t lds_hx[64 * 256];        // 32 KB
    __shared__ __align__(16) half_t lds_xp[8 * 32 * 64 * 4]; // 128 KB

    const int tid = threadIdx.x;
    const int w  = tid >> 6;   // wave 0..7 owns h-cols [w*32, w*32+32)
    const int l  = tid & 63;
    const int lm = l & 15;
    const int lg = l >> 4;

    const int row0 = blockIdx.x * 64;     // 200 blocks * 64 rows = 12800
    const int bb_  = row0 / 1600;         // batch (no tile crosses a batch)
    const int p0   = row0 % 1600;

    // ---- stage x tile (A operand of phase 0) into lds_hx, f16 swizzled ----
    {
        const float* xin = x + (size_t)bb_ * 409600 + p0;   // x[b][c][p0+p]
        for (int it = 0; it < 32; ++it) {
            int idx = it * 512 + tid;
            int p = idx & 63, c = idx >> 6;
            lds_hx[p * 256 + (c ^ ((p & 7) << 2))] = (half_t)xin[c * 1600 + p];
        }
    }
    __syncthreads();

    // per-wave N-tile table: n = gate*2+np -> 16-row tile of W, and column j
    int Tn[8], jcol[8];
#pragma unroll
    for (int n = 0; n < 8; ++n) {
        Tn[n]   = (n >> 1) * 16 + w * 2 + (n & 1);
        jcol[n] = Tn[n] * 16 + lm;    // = gate*256 + w*32 + (n&1)*16 + lm
    }

    f32x4 acc[32];

    // ---------------- phase 0: x_proj ----------------
#pragma unroll
    for (int n = 0; n < 8; ++n) {
        float bias = b_ih[jcol[n]] + b_hh[jcol[n]];
#pragma unroll
        for (int mt = 0; mt < 4; ++mt)
            acc[mt * 8 + n] = (f32x4){bias, bias, bias, bias};
    }
    gemm_ktile(acc, lds_hx, Wih_s, Tn, lm, lg, l);

    // dump x_proj to own-wave LDS region as f16 (read back with same pattern)
#pragma unroll
    for (int f = 0; f < 32; ++f) {
        half4v xv;
#pragma unroll
        for (int r = 0; r < 4; ++r) xv[r] = (half_t)acc[f][r];
        *reinterpret_cast<half4v*>(&lds_xp[((w * 32 + f) * 64 + l) * 4]) = xv;
    }

    __syncthreads();   // everyone done reading the x tile in lds_hx

    // ---- stage h0 into lds_hx; load cx into registers (C/D layout) ----
    {
        const float* hin = hx0 + (size_t)row0 * 256;
        for (int it = 0; it < 32; ++it) {
            int idx = it * 512 + tid;
            int p = idx & 63, c = idx >> 6;
            lds_hx[p * 256 + (c ^ ((p & 7) << 2))] = (half_t)hin[p * 256 + c];
        }
    }
    float cxr[32];
#pragma unroll
    for (int mt = 0; mt < 4; ++mt)
#pragma unroll
        for (int np = 0; np < 2; ++np)
#pragma unroll
            for (int r = 0; r < 4; ++r) {
                int p = mt * 16 + lg * 4 + r;
                int c = w * 32 + np * 16 + lm;
                cxr[(mt * 2 + np) * 4 + r] = cx0[(size_t)(row0 + p) * 256 + c];
            }
    __syncthreads();

    // ---------------- 16 recurrent steps ----------------
    for (int t = 0; t < 16; ++t) {
        // acc init = x_proj (from own-wave frag dump)
#pragma unroll
        for (int f = 0; f < 32; ++f) {
            half4v u = *reinterpret_cast<const half4v*>(
                &lds_xp[((w * 32 + f) * 64 + l) * 4]);
#pragma unroll
            for (int r = 0; r < 4; ++r) acc[f][r] = (float)u[r];
        }

        gemm_ktile(acc, lds_hx, Whh_s, Tn, lm, lg, l);

        __syncthreads();   // all waves finished reading lds_hx(t)

        // gates -> cx,hx ; write hx(t+1) into lds_hx (f16, swizzled)
#pragma unroll
        for (int mt = 0; mt < 4; ++mt)
#pragma unroll
            for (int np = 0; np < 2; ++np)
#pragma unroll
                for (int r = 0; r < 4; ++r) {
                    float iv = acc[mt * 8 + 0 + np][r];
                    float fv = acc[mt * 8 + 2 + np][r];
                    float gv = acc[mt * 8 + 4 + np][r];
                    float ov = acc[mt * 8 + 6 + np][r];
                    float si = fast_sigmoid(iv);
                    float sf = fast_sigmoid(fv);
                    float tg = fast_tanh(gv);
                    float so = fast_sigmoid(ov);
                    int ci = (mt * 2 + np) * 4 + r;
                    float cxn = sf * cxr[ci] + si * tg;
                    cxr[ci] = cxn;
                    float h = so * fast_tanh(cxn);
                    int p  = mt * 16 + lg * 4 + r;
                    int cc = w * 32 + np * 16 + lm;
                    lds_hx[p * 256 + (cc ^ ((p & 7) << 2))] = (half_t)h;
                }
        __syncthreads();   // hx(t+1) visible to all

        // head: y = leaky_relu(hx) @ W_lin^T + b_lin, write [n][t][o]
        {
            const int p = tid >> 3;          // row 0..63
            const int o = (tid >> 2) & 1;    // output 0..1
            const int q = tid & 3;           // quarter of the 256 h-cols
            const float* wl = W_lin + o * 256;
            float s = 0.0f;
#pragma unroll
            for (int cb = 0; cb < 16; ++cb) {
                int c0 = q * 64 + cb * 4;
                half4v u = *reinterpret_cast<const half4v*>(
                    &lds_hx[p * 256 + (c0 ^ ((p & 7) << 2))]);
                float4 wv = *reinterpret_cast<const float4*>(wl + c0);
                float h0 = (float)u[0], h1 = (float)u[1];
                float h2 = (float)u[2], h3 = (float)u[3];
                s += fmaxf(h0, 0.01f * h0) * wv.x;
                s += fmaxf(h1, 0.01f * h1) * wv.y;
                s += fmaxf(h2, 0.01f * h2) * wv.z;
                s += fmaxf(h3, 0.01f * h3) * wv.w;
            }
            s += __shfl_xor(s, 1);
            s += __shfl_xor(s, 2);
            if (q == 0)
                out[((size_t)(row0 + p) * 16 + t) * 2 + o] = s + b_lin[o];
        }
    }
}

// ---------------------------------------------------------------------------
extern "C" void kernel_launch(void* const* d_in, const int* in_sizes, int n_in,
                              void* d_out, int out_size, void* d_ws, size_t ws_size,
                              hipStream_t stream)
{
    const float* x    = (const float*)d_in[0];
    const float* hx   = (const float*)d_in[1];
    const float* cx   = (const float*)d_in[2];
    const float* Wih  = (const float*)d_in[3];
    const float* Whh  = (const float*)d_in[4];
    const float* bih  = (const float*)d_in[5];
    const float* bhh  = (const float*)d_in[6];
    const float* Wlin = (const float*)d_in[7];
    const float* blin = (const float*)d_in[8];
    float* out = (float*)d_out;

    // workspace: two shuffled f16 weight matrices, 512 KB each
    half_t* wih_s = (half_t*)d_ws;
    half_t* whh_s = wih_s + 1024 * 256;

    shuffle_w_kernel<<<512, 64, 0, stream>>>(Wih, wih_s);
    shuffle_w_kernel<<<512, 64, 0, stream>>>(Whh, whh_s);
    lstm_kernel<<<200, 512, 0, stream>>>(x, hx, cx, bih, bhh, Wlin, blin,
                                         wih_s, whh_s, out);
}

// Round 2
// 722.709 us; speedup vs baseline: 1.2660x; 1.2660x over previous
//
#include <hip/hip_runtime.h>
#include <stdint.h>
#include <stddef.h>

// ---------- types ----------
typedef _Float16 half_t;
typedef half_t half8  __attribute__((ext_vector_type(8)));
typedef half_t half4v __attribute__((ext_vector_type(4)));
typedef float  f32x4  __attribute__((ext_vector_type(4)));

__device__ __forceinline__ float fast_sigmoid(float x) {
    float e = __builtin_amdgcn_exp2f(-1.44269504f * x);
    return __builtin_amdgcn_rcpf(1.0f + e);
}
__device__ __forceinline__ float fast_tanh(float x) {
    // tanh(x) = 1 - 2/(exp(2x)+1)
    float e = __builtin_amdgcn_exp2f(2.88539008f * x);
    return 1.0f - 2.0f * __builtin_amdgcn_rcpf(1.0f + e);
}

// ---------------------------------------------------------------------------
// Prep: reorder W [1024][256] f32 (row-major) into MFMA-B fragment order, f16.
// For j-tile T=j/16 (64), k-tile kt=k/32 (8), lane l (64): 8 halves at
// ((T*8+kt)*64 + l)*8 :
//   elems 0..3 : k = kt*32 +      (l>>4)*4 + e ,  j = T*16 + (l&15)
//   elems 4..7 : k = kt*32 + 16 + (l>>4)*4 + e
// Same (lane-group,reg)->k bijection used for A from LDS (validated R1:
// absmax 2e-3), so the contraction pairs correctly.
// ---------------------------------------------------------------------------
__global__ __launch_bounds__(64) void shuffle_w_kernel(
    const float* __restrict__ W, half_t* __restrict__ out)
{
    const int blk = blockIdx.x;         // 512 = 64 T * 8 kt
    const int T = blk >> 3, kt = blk & 7;
    const int l = threadIdx.x;
    const int j  = T * 16 + (l & 15);
    const int kb = kt * 32 + ((l >> 4) << 2);
    half8 v;
#pragma unroll
    for (int h = 0; h < 2; ++h)
#pragma unroll
        for (int e = 0; e < 4; ++e)
            v[h * 4 + e] = (half_t)W[j * 256 + kb + h * 16 + e];
    *reinterpret_cast<half8*>(out + (size_t)(blk * 64 + l) * 8) = v;
}

// ---------------------------------------------------------------------------
// One K=256 GEMM accumulation for one wave's 4 N-tiles (one per gate):
// acc[mt*4+g] += hx_tile(64x256) @ W^T tile Tn[g].
// A from LDS (XOR-swizzled rows), B from pre-shuffled global (L2-resident).
// ---------------------------------------------------------------------------
__device__ __forceinline__ void gemm_ktile(
    f32x4* acc, const half_t* __restrict__ lhx,
    const half_t* __restrict__ Ws, const int* Tn,
    int lm, int lg, int l)
{
#pragma unroll
    for (int kt = 0; kt < 8; ++kt) {
        half8 a[4];
#pragma unroll
        for (int mt = 0; mt < 4; ++mt) {
            const int p   = mt * 16 + lm;
            const int swz = (p & 7) << 2;           // XOR-swizzle, half-units
            const int k0  = kt * 32 + lg * 4;
            union { half8 v; half4v h[2]; } t;
            t.h[0] = *reinterpret_cast<const half4v*>(&lhx[p * 256 + ((k0     ) ^ swz)]);
            t.h[1] = *reinterpret_cast<const half4v*>(&lhx[p * 256 + ((k0 + 16) ^ swz)]);
            a[mt] = t.v;
        }
#pragma unroll
        for (int g = 0; g < 4; ++g) {
            half8 bb = *reinterpret_cast<const half8*>(
                &Ws[(size_t)((Tn[g] * 8 + kt) * 64 + l) * 8]);
#pragma unroll
            for (int mt = 0; mt < 4; ++mt)
                acc[mt * 4 + g] = __builtin_amdgcn_mfma_f32_16x16x32_f16(
                    a[mt], bb, acc[mt * 4 + g], 0, 0, 0);
        }
    }
}

// ---------------------------------------------------------------------------
// Persistent LSTM: block = 64 rows x 16 steps, 16 waves (1024 threads).
// Wave w owns gate cols { g*256 + w*16 .. +16 } for g=0..3 (Tn[g]=g*16+w),
// so each thread holds i,f,g,o for its (row,col) pairs -> thread-local cell
// update, acc = 16 f32x4 = 64 VGPRs (fits the 128-VGPR/4-wave-SIMD cap).
// LDS: hx 64x256 f16 = 32 KB (XOR-swizzled), x_proj frag dump = 128 KB.
// ---------------------------------------------------------------------------
__global__ __launch_bounds__(1024, 4) void lstm_kernel(
    const float* __restrict__ x,      // [8][256][1600]
    const float* __restrict__ hx0,    // [12800][256]
    const float* __restrict__ cx0,    // [12800][256]
    const float* __restrict__ b_ih,   // [1024]
    const float* __restrict__ b_hh,   // [1024]
    const float* __restrict__ W_lin,  // [2][256]
    const float* __restrict__ b_lin,  // [2]
    const half_t* __restrict__ Wih_s, // shuffled f16
    const half_t* __restrict__ Whh_s, // shuffled f16
    float* __restrict__ out)          // [12800][16][2]
{
    __shared__ __align__(16) half_t lds_hx[64 * 256];         // 32 KB
    __shared__ __align__(16) half_t lds_xp[16 * 16 * 64 * 4]; // 128 KB

    const int tid = threadIdx.x;
    const int w  = tid >> 6;   // wave 0..15
    const int l  = tid & 63;
    const int lm = l & 15;
    const int lg = l >> 4;

    const int row0 = blockIdx.x * 64;     // 200 blocks * 64 rows = 12800
    const int bb_  = row0 / 1600;         // batch (no tile crosses a batch)
    const int p0   = row0 % 1600;

    // ---- stage x tile into lds_hx, f16 swizzled (coalesced on p) ----
    {
        const float* xin = x + (size_t)bb_ * 409600 + p0;   // x[b][c][p0+p]
        for (int it = 0; it < 16; ++it) {
            int idx = it * 1024 + tid;
            int p = idx & 63, c = idx >> 6;
            lds_hx[p * 256 + (c ^ ((p & 7) << 2))] = (half_t)xin[c * 1600 + p];
        }
    }
    __syncthreads();

    int Tn[4];
#pragma unroll
    for (int g = 0; g < 4; ++g) Tn[g] = g * 16 + w;

    f32x4 acc[16];

    // ---------------- phase 0: x_proj = x @ W_ih^T + b_ih + b_hh ----------
#pragma unroll
    for (int g = 0; g < 4; ++g) {
        int col = g * 256 + w * 16 + lm;
        float bias = b_ih[col] + b_hh[col];
#pragma unroll
        for (int mt = 0; mt < 4; ++mt)
            acc[mt * 4 + g] = (f32x4){bias, bias, bias, bias};
    }
    gemm_ktile(acc, lds_hx, Wih_s, Tn, lm, lg, l);

    // dump x_proj to own-wave LDS region as f16 (read back identically)
#pragma unroll
    for (int f = 0; f < 16; ++f) {
        half4v xv;
#pragma unroll
        for (int r = 0; r < 4; ++r) xv[r] = (half_t)acc[f][r];
        *reinterpret_cast<half4v*>(&lds_xp[((w * 16 + f) * 64 + l) * 4]) = xv;
    }

    __syncthreads();   // everyone done reading the x tile in lds_hx

    // ---- stage h0 into lds_hx (coalesced on c); cx into registers ----
    {
        const float* hin = hx0 + (size_t)row0 * 256;
        for (int it = 0; it < 16; ++it) {
            int idx = it * 1024 + tid;
            int c = idx & 255, p = idx >> 8;
            lds_hx[p * 256 + (c ^ ((p & 7) << 2))] = (half_t)hin[p * 256 + c];
        }
    }
    float cxr[16];
#pragma unroll
    for (int mt = 0; mt < 4; ++mt)
#pragma unroll
        for (int r = 0; r < 4; ++r) {
            int p = mt * 16 + lg * 4 + r;
            int c = w * 16 + lm;
            cxr[mt * 4 + r] = cx0[(size_t)(row0 + p) * 256 + c];
        }
    __syncthreads();

    // ---------------- 16 recurrent steps ----------------
    for (int t = 0; t < 16; ++t) {
        // acc init = x_proj (own-wave frag dump)
#pragma unroll
        for (int f = 0; f < 16; ++f) {
            half4v u = *reinterpret_cast<const half4v*>(
                &lds_xp[((w * 16 + f) * 64 + l) * 4]);
#pragma unroll
            for (int r = 0; r < 4; ++r) acc[f][r] = (float)u[r];
        }

        gemm_ktile(acc, lds_hx, Whh_s, Tn, lm, lg, l);

        __syncthreads();   // all waves finished reading lds_hx(t)

        // gates -> cx,hx ; write hx(t+1) into lds_hx (f16, swizzled)
#pragma unroll
        for (int mt = 0; mt < 4; ++mt)
#pragma unroll
            for (int r = 0; r < 4; ++r) {
                float iv = acc[mt * 4 + 0][r];
                float fv = acc[mt * 4 + 1][r];
                float gv = acc[mt * 4 + 2][r];
                float ov = acc[mt * 4 + 3][r];
                float si = fast_sigmoid(iv);
                float sf = fast_sigmoid(fv);
                float tg = fast_tanh(gv);
                float so = fast_sigmoid(ov);
                float cxn = sf * cxr[mt * 4 + r] + si * tg;
                cxr[mt * 4 + r] = cxn;
                float h = so * fast_tanh(cxn);
                int p  = mt * 16 + lg * 4 + r;
                int cc = w * 16 + lm;
                lds_hx[p * 256 + (cc ^ ((p & 7) << 2))] = (half_t)h;
            }
        __syncthreads();   // hx(t+1) visible to all

        // head: y = leaky_relu(hx) @ W_lin^T + b_lin, write [n][t][o]
        {
            const int p = tid >> 4;          // row 0..63
            const int o = (tid >> 3) & 1;    // output 0..1
            const int q = tid & 7;           // eighth of the 256 h-cols
            const float* wl = W_lin + o * 256;
            float s = 0.0f;
#pragma unroll
            for (int cb = 0; cb < 8; ++cb) {
                int c0 = q * 32 + cb * 4;
                half4v u = *reinterpret_cast<const half4v*>(
                    &lds_hx[p * 256 + (c0 ^ ((p & 7) << 2))]);
                float4 wv = *reinterpret_cast<const float4*>(wl + c0);
                float h0 = (float)u[0], h1 = (float)u[1];
                float h2 = (float)u[2], h3 = (float)u[3];
                s += fmaxf(h0, 0.01f * h0) * wv.x;
                s += fmaxf(h1, 0.01f * h1) * wv.y;
                s += fmaxf(h2, 0.01f * h2) * wv.z;
                s += fmaxf(h3, 0.01f * h3) * wv.w;
            }
            s += __shfl_xor(s, 1);
            s += __shfl_xor(s, 2);
            s += __shfl_xor(s, 4);
            if (q == 0)
                out[((size_t)(row0 + p) * 16 + t) * 2 + o] = s + b_lin[o];
        }
    }
}

// ---------------------------------------------------------------------------
extern "C" void kernel_launch(void* const* d_in, const int* in_sizes, int n_in,
                              void* d_out, int out_size, void* d_ws, size_t ws_size,
                              hipStream_t stream)
{
    const float* x    = (const float*)d_in[0];
    const float* hx   = (const float*)d_in[1];
    const float* cx   = (const float*)d_in[2];
    const float* Wih  = (const float*)d_in[3];
    const float* Whh  = (const float*)d_in[4];
    const float* bih  = (const float*)d_in[5];
    const float* bhh  = (const float*)d_in[6];
    const float* Wlin = (const float*)d_in[7];
    const float* blin = (const float*)d_in[8];
    float* out = (float*)d_out;

    // workspace: two shuffled f16 weight matrices, 512 KB each
    half_t* wih_s = (half_t*)d_ws;
    half_t* whh_s = wih_s + 1024 * 256;

    shuffle_w_kernel<<<512, 64, 0, stream>>>(Wih, wih_s);
    shuffle_w_kernel<<<512, 64, 0, stream>>>(Whh, whh_s);
    lstm_kernel<<<200, 1024, 0, stream>>>(x, hx, cx, bih, bhh, Wlin, blin,
                                          wih_s, whh_s, out);
}

// Round 3
// 538.887 us; speedup vs baseline: 1.6979x; 1.3411x over previous
//
#include <hip/hip_runtime.h>
#include <stdint.h>
#include <stddef.h>

// ---------- types ----------
typedef _Float16 half_t;
typedef half_t half8  __attribute__((ext_vector_type(8)));
typedef half_t half4v __attribute__((ext_vector_type(4)));
typedef float  f32x4  __attribute__((ext_vector_type(4)));

__device__ __forceinline__ float fast_sigmoid(float x) {
    float e = __builtin_amdgcn_exp2f(-1.44269504f * x);
    return __builtin_amdgcn_rcpf(1.0f + e);
}
__device__ __forceinline__ float fast_tanh(float x) {
    float e = __builtin_amdgcn_exp2f(2.88539008f * x);
    return 1.0f - 2.0f * __builtin_amdgcn_rcpf(1.0f + e);
}

// ---------------------------------------------------------------------------
// Prep: W [1024][256] f32 row-major -> MFMA-B fragment order, f16.
// Bijection (contiguous k): lane l, elem e of tile (T,kt) holds
//   B[k = kt*32 + (l>>4)*8 + e, j = T*16 + (l&15)].
// A-fragments from LDS use the SAME (lane-group,elem)->k mapping, so the
// contraction pairs correctly (A/B layouts are mirrored; R1 validated the
// same-bijection principle, absmax 2e-3).
// ---------------------------------------------------------------------------
__global__ __launch_bounds__(64) void shuffle_w_kernel(
    const float* __restrict__ W, half_t* __restrict__ out)
{
    const int blk = blockIdx.x;         // 512 = 64 T * 8 kt
    const int T = blk >> 3, kt = blk & 7;
    const int l = threadIdx.x;
    const int j = T * 16 + (l & 15);
    const int k0 = kt * 32 + ((l >> 4) << 3);
    half8 v;
#pragma unroll
    for (int e = 0; e < 8; ++e) v[e] = (half_t)W[j * 256 + k0 + e];
    *reinterpret_cast<half8*>(out + (size_t)(blk * 64 + l) * 8) = v;
}

// ---------------------------------------------------------------------------
// One 2-gate GEMM pass: acc[mt*2+{0,1}] += hx(64x256) @ W^T tiles {t0,t1}.
// A: one ds_read_b128 per (mt,kt), XOR-swizzle (p&7)<<4 half-units (2-way
// bank aliasing = free). B: coalesced 16B/lane from pre-shuffled global.
// ---------------------------------------------------------------------------
__device__ __forceinline__ void gemm_pass(
    f32x4* acc, const half_t* __restrict__ lhx,
    const half_t* __restrict__ Ws, int t0, int t1, int lm, int lg, int l)
{
#pragma unroll
    for (int kt = 0; kt < 8; ++kt) {
        half8 a[4];
#pragma unroll
        for (int mt = 0; mt < 4; ++mt) {
            const int p = mt * 16 + lm;
            const int k = (kt * 32 + lg * 8) ^ ((p & 7) << 4);
            a[mt] = *reinterpret_cast<const half8*>(&lhx[p * 256 + k]);
        }
        half8 b0 = *reinterpret_cast<const half8*>(
            &Ws[(size_t)((t0 * 8 + kt) * 64 + l) * 8]);
        half8 b1 = *reinterpret_cast<const half8*>(
            &Ws[(size_t)((t1 * 8 + kt) * 64 + l) * 8]);
#pragma unroll
        for (int mt = 0; mt < 4; ++mt) {
            acc[mt * 2 + 0] = __builtin_amdgcn_mfma_f32_16x16x32_f16(
                a[mt], b0, acc[mt * 2 + 0], 0, 0, 0);
            acc[mt * 2 + 1] = __builtin_amdgcn_mfma_f32_16x16x32_f16(
                a[mt], b1, acc[mt * 2 + 1], 0, 0, 0);
        }
    }
}

// ---------------------------------------------------------------------------
// Persistent LSTM: block = 64 rows x 16 steps, 16 waves (1024 threads).
// Two passes per step: (i,g) -> p1 = sig(i)*tanh(g); (f,o) -> cell update.
// Wave w owns h-cols [w*16, w*16+16); per pass acc = 8 frags = 32 regs,
// peak ~100 unified regs < 128 cap -> no spills (R2's failure mode).
// LDS: hx 32 KB (XOR-swizzled rows) + x_proj frag dump 128 KB = 160 KB.
// ---------------------------------------------------------------------------
__global__ __launch_bounds__(1024, 4) void lstm_kernel(
    const float* __restrict__ x,      // [8][256][1600]
    const float* __restrict__ hx0,    // [12800][256]
    const float* __restrict__ cx0,    // [12800][256]
    const float* __restrict__ b_ih,   // [1024]
    const float* __restrict__ b_hh,   // [1024]
    const float* __restrict__ W_lin,  // [2][256]
    const float* __restrict__ b_lin,  // [2]
    const half_t* __restrict__ Wih_s, // shuffled f16
    const half_t* __restrict__ Whh_s, // shuffled f16
    float* __restrict__ out)          // [12800][16][2]
{
    __shared__ __align__(16) half_t lds_hx[64 * 256];         // 32 KB
    __shared__ __align__(16) half_t lds_xp[16 * 16 * 64 * 4]; // 128 KB

    const int tid = threadIdx.x;
    const int w  = tid >> 6;   // wave 0..15 owns h-cols [w*16, w*16+16)
    const int l  = tid & 63;
    const int lm = l & 15;
    const int lg = l >> 4;

    const int row0 = blockIdx.x * 64;     // 200 blocks * 64 rows
    const int bb_  = row0 / 1600;
    const int p0   = row0 % 1600;

    // gate tile indices: gates [i,f,g,o] at col blocks 0/256/512/768
    const int tA0 = w,      tA1 = 32 + w;   // i, g
    const int tB0 = 16 + w, tB1 = 48 + w;   // f, o

    // ---- stage x tile into lds_hx, f16 swizzled (coalesced on p) ----
    {
        const float* xin = x + (size_t)bb_ * 409600 + p0;   // x[b][c][p0+p]
        for (int it = 0; it < 16; ++it) {
            int idx = it * 1024 + tid;
            int p = idx & 63, c = idx >> 6;
            lds_hx[p * 256 + (c ^ ((p & 7) << 4))] = (half_t)xin[c * 1600 + p];
        }
    }
    __syncthreads();

    // ---------------- phase 0: x_proj = x @ W_ih^T + b_ih + b_hh ----------
    {
        f32x4 acc[8];
#pragma unroll
        for (int pass = 0; pass < 2; ++pass) {
            int t0 = pass ? tB0 : tA0, t1 = pass ? tB1 : tA1;
#pragma unroll
            for (int gi = 0; gi < 2; ++gi) {
                int col = (pass ? (gi ? tB1 : tB0) : (gi ? tA1 : tA0)) * 16 + lm;
                float bias = b_ih[col] + b_hh[col];
#pragma unroll
                for (int mt = 0; mt < 4; ++mt)
                    acc[mt * 2 + gi] = (f32x4){bias, bias, bias, bias};
            }
            gemm_pass(acc, lds_hx, Wih_s, t0, t1, lm, lg, l);
#pragma unroll
            for (int f = 0; f < 8; ++f) {
                half4v xv;
#pragma unroll
                for (int r = 0; r < 4; ++r) xv[r] = (half_t)acc[f][r];
                *reinterpret_cast<half4v*>(
                    &lds_xp[((w * 16 + pass * 8 + f) * 64 + l) * 4]) = xv;
            }
        }
    }
    __syncthreads();   // x tile fully consumed, xp written

    // ---- stage h0 into lds_hx (coalesced on c); cx into registers ----
    {
        const float* hin = hx0 + (size_t)row0 * 256;
        for (int it = 0; it < 16; ++it) {
            int idx = it * 1024 + tid;
            int c = idx & 255, p = idx >> 8;
            lds_hx[p * 256 + (c ^ ((p & 7) << 4))] = (half_t)hin[p * 256 + c];
        }
    }
    float cxr[16];
#pragma unroll
    for (int mt = 0; mt < 4; ++mt)
#pragma unroll
        for (int r = 0; r < 4; ++r) {
            int p = mt * 16 + lg * 4 + r;
            cxr[mt * 4 + r] = cx0[(size_t)(row0 + p) * 256 + w * 16 + lm];
        }
    __syncthreads();

    // ---------------- 16 recurrent steps ----------------
    for (int t = 0; t < 16; ++t) {
        f32x4 acc[8];
        float p1[16];

        // ---- pass A: gates i,g ----
#pragma unroll
        for (int f = 0; f < 8; ++f) {
            half4v u = *reinterpret_cast<const half4v*>(
                &lds_xp[((w * 16 + f) * 64 + l) * 4]);
#pragma unroll
            for (int r = 0; r < 4; ++r) acc[f][r] = (float)u[r];
        }
        gemm_pass(acc, lds_hx, Whh_s, tA0, tA1, lm, lg, l);
#pragma unroll
        for (int mt = 0; mt < 4; ++mt)
#pragma unroll
            for (int r = 0; r < 4; ++r)
                p1[mt * 4 + r] = fast_sigmoid(acc[mt * 2 + 0][r]) *
                                 fast_tanh(acc[mt * 2 + 1][r]);

        // ---- pass B: gates f,o ----
#pragma unroll
        for (int f = 0; f < 8; ++f) {
            half4v u = *reinterpret_cast<const half4v*>(
                &lds_xp[((w * 16 + 8 + f) * 64 + l) * 4]);
#pragma unroll
            for (int r = 0; r < 4; ++r) acc[f][r] = (float)u[r];
        }
        gemm_pass(acc, lds_hx, Whh_s, tB0, tB1, lm, lg, l);

        __syncthreads();   // all waves finished reading lds_hx(t)

        // cell update; write hx(t+1) into lds_hx (f16, swizzled)
#pragma unroll
        for (int mt = 0; mt < 4; ++mt)
#pragma unroll
            for (int r = 0; r < 4; ++r) {
                float sf = fast_sigmoid(acc[mt * 2 + 0][r]);
                float so = fast_sigmoid(acc[mt * 2 + 1][r]);
                float cxn = sf * cxr[mt * 4 + r] + p1[mt * 4 + r];
                cxr[mt * 4 + r] = cxn;
                float h = so * fast_tanh(cxn);
                int p = mt * 16 + lg * 4 + r;
                lds_hx[p * 256 + ((w * 16 + lm) ^ ((p & 7) << 4))] = (half_t)h;
            }
        __syncthreads();   // hx(t+1) visible to all

        // head: y = leaky_relu(hx) @ W_lin^T + b_lin, write [n][t][o]
        {
            const int p = tid >> 4;          // row 0..63
            const int o = (tid >> 3) & 1;    // output 0..1
            const int q = tid & 7;           // eighth of the 256 h-cols
            const float* wl = W_lin + o * 256;
            float s = 0.0f;
#pragma unroll
            for (int cb = 0; cb < 8; ++cb) {
                int c0 = q * 32 + cb * 4;
                half4v u = *reinterpret_cast<const half4v*>(
                    &lds_hx[p * 256 + (c0 ^ ((p & 7) << 4))]);
                float4 wv = *reinterpret_cast<const float4*>(wl + c0);
                float h0 = (float)u[0], h1 = (float)u[1];
                float h2 = (float)u[2], h3 = (float)u[3];
                s += fmaxf(h0, 0.01f * h0) * wv.x;
                s += fmaxf(h1, 0.01f * h1) * wv.y;
                s += fmaxf(h2, 0.01f * h2) * wv.z;
                s += fmaxf(h3, 0.01f * h3) * wv.w;
            }
            s += __shfl_xor(s, 1);
            s += __shfl_xor(s, 2);
            s += __shfl_xor(s, 4);
            if (q == 0)
                out[((size_t)(row0 + p) * 16 + t) * 2 + o] = s + b_lin[o];
        }
    }
}

// ---------------------------------------------------------------------------
extern "C" void kernel_launch(void* const* d_in, const int* in_sizes, int n_in,
                              void* d_out, int out_size, void* d_ws, size_t ws_size,
                              hipStream_t stream)
{
    const float* x    = (const float*)d_in[0];
    const float* hx   = (const float*)d_in[1];
    const float* cx   = (const float*)d_in[2];
    const float* Wih  = (const float*)d_in[3];
    const float* Whh  = (const float*)d_in[4];
    const float* bih  = (const float*)d_in[5];
    const float* bhh  = (const float*)d_in[6];
    const float* Wlin = (const float*)d_in[7];
    const float* blin = (const float*)d_in[8];
    float* out = (float*)d_out;

    half_t* wih_s = (half_t*)d_ws;             // 512 KB
    half_t* whh_s = wih_s + 1024 * 256;        // 512 KB

    shuffle_w_kernel<<<512, 64, 0, stream>>>(Wih, wih_s);
    shuffle_w_kernel<<<512, 64, 0, stream>>>(Whh, whh_s);
    lstm_kernel<<<200, 1024, 0, stream>>>(x, hx, cx, bih, bhh, Wlin, blin,
                                          wih_s, whh_s, out);
}

// Round 4
// 288.584 us; speedup vs baseline: 3.1705x; 1.8673x over previous
//
#include <hip/hip_runtime.h>
#include <stdint.h>
#include <stddef.h>

// ---------- types ----------
typedef _Float16 half_t;
typedef half_t half8  __attribute__((ext_vector_type(8)));
typedef half_t half4v __attribute__((ext_vector_type(4)));
typedef float  f32x4  __attribute__((ext_vector_type(4)));

__device__ __forceinline__ float fast_sigmoid(float x) {
    float e = __builtin_amdgcn_exp2f(-1.44269504f * x);
    return __builtin_amdgcn_rcpf(1.0f + e);
}
__device__ __forceinline__ float fast_tanh(float x) {
    float e = __builtin_amdgcn_exp2f(2.88539008f * x);
    return 1.0f - 2.0f * __builtin_amdgcn_rcpf(1.0f + e);
}

// ---------------------------------------------------------------------------
// Prep: W [1024][256] f32 row-major -> MFMA-B fragment order, f16.
// Bijection (contiguous k): lane l, elem e of tile (T,kt) holds
//   B[k = kt*32 + (l>>4)*8 + e, j = T*16 + (l&15)].
// A-fragments from LDS use the SAME (lane-group,elem)->k mapping (validated
// R1/R3: absmax 2e-3).
// ---------------------------------------------------------------------------
__global__ __launch_bounds__(64) void shuffle_w_kernel(
    const float* __restrict__ W, half_t* __restrict__ out)
{
    const int blk = blockIdx.x;         // 512 = 64 T * 8 kt
    const int T = blk >> 3, kt = blk & 7;
    const int l = threadIdx.x;
    const int j = T * 16 + (l & 15);
    const int k0 = kt * 32 + ((l >> 4) << 3);
    half8 v;
#pragma unroll
    for (int e = 0; e < 8; ++e) v[e] = (half_t)W[j * 256 + k0 + e];
    *reinterpret_cast<half8*>(out + (size_t)(blk * 64 + l) * 8) = v;
}

// ---------------------------------------------------------------------------
// One 2-gate GEMM pass: acc[mt*2+{0,1}] += hx(64x256) @ W^T tiles {t0,t1}.
// kt loop deliberately NOT unrolled + sched_barrier(0) per iteration: caps
// the scheduler's load-hoisting window so the live set stays ~70 regs.
// (R2/R3 post-mortem: full unroll -> ~190 transient regs -> ~30-slot scratch
// spill -> 380 MB scratch writes + L2 thrash. This pin is the fix.)
// ---------------------------------------------------------------------------
__device__ __forceinline__ void gemm_pass(
    f32x4* acc, const half_t* __restrict__ lhx,
    const half_t* __restrict__ Ws, int t0, int t1, int lm, int lg, int l)
{
#pragma unroll 1
    for (int kt = 0; kt < 8; ++kt) {
        half8 a[4];
#pragma unroll
        for (int mt = 0; mt < 4; ++mt) {
            const int p = mt * 16 + lm;
            const int k = (kt * 32 + lg * 8) ^ ((p & 7) << 4);
            a[mt] = *reinterpret_cast<const half8*>(&lhx[p * 256 + k]);
        }
        half8 b0 = *reinterpret_cast<const half8*>(
            &Ws[(size_t)((t0 * 8 + kt) * 64 + l) * 8]);
        half8 b1 = *reinterpret_cast<const half8*>(
            &Ws[(size_t)((t1 * 8 + kt) * 64 + l) * 8]);
#pragma unroll
        for (int mt = 0; mt < 4; ++mt) {
            acc[mt * 2 + 0] = __builtin_amdgcn_mfma_f32_16x16x32_f16(
                a[mt], b0, acc[mt * 2 + 0], 0, 0, 0);
            acc[mt * 2 + 1] = __builtin_amdgcn_mfma_f32_16x16x32_f16(
                a[mt], b1, acc[mt * 2 + 1], 0, 0, 0);
        }
        __builtin_amdgcn_sched_barrier(0);   // no motion across kt iterations
    }
}

// ---------------------------------------------------------------------------
// Persistent LSTM: block = 64 rows x 16 steps, 16 waves (1024 threads).
// Two passes per step: (i,g) -> p1 = sig(i)*tanh(g); (f,o) -> cell update.
// Wave w owns h-cols [w*16, w*16+16); per pass acc = 8 frags = 32 regs.
// LDS: hx 32 KB (XOR-swizzled rows) + x_proj frag dump 128 KB = 160 KB.
// ---------------------------------------------------------------------------
__global__ __launch_bounds__(1024, 4) void lstm_kernel(
    const float* __restrict__ x,      // [8][256][1600]
    const float* __restrict__ hx0,    // [12800][256]
    const float* __restrict__ cx0,    // [12800][256]
    const float* __restrict__ b_ih,   // [1024]
    const float* __restrict__ b_hh,   // [1024]
    const float* __restrict__ W_lin,  // [2][256]
    const float* __restrict__ b_lin,  // [2]
    const half_t* __restrict__ Wih_s, // shuffled f16
    const half_t* __restrict__ Whh_s, // shuffled f16
    float* __restrict__ out)          // [12800][16][2]
{
    __shared__ __align__(16) half_t lds_hx[64 * 256];         // 32 KB
    __shared__ __align__(16) half_t lds_xp[16 * 16 * 64 * 4]; // 128 KB

    const int tid = threadIdx.x;
    const int w  = tid >> 6;   // wave 0..15 owns h-cols [w*16, w*16+16)
    const int l  = tid & 63;
    const int lm = l & 15;
    const int lg = l >> 4;

    const int row0 = blockIdx.x * 64;     // 200 blocks * 64 rows
    const int bb_  = row0 / 1600;
    const int p0   = row0 % 1600;

    // gate tile indices: gates [i,f,g,o] at col blocks 0/256/512/768
    const int tA0 = w,      tA1 = 32 + w;   // i, g
    const int tB0 = 16 + w, tB1 = 48 + w;   // f, o

    // ---- stage x tile into lds_hx, f16 swizzled (coalesced on p) ----
    {
        const float* xin = x + (size_t)bb_ * 409600 + p0;   // x[b][c][p0+p]
        for (int it = 0; it < 16; ++it) {
            int idx = it * 1024 + tid;
            int p = idx & 63, c = idx >> 6;
            lds_hx[p * 256 + (c ^ ((p & 7) << 4))] = (half_t)xin[c * 1600 + p];
        }
    }
    __syncthreads();

    // ---------------- phase 0: x_proj = x @ W_ih^T + b_ih + b_hh ----------
    {
        f32x4 acc[8];
#pragma unroll 1
        for (int pass = 0; pass < 2; ++pass) {
            int t0 = pass ? tB0 : tA0, t1 = pass ? tB1 : tA1;
#pragma unroll
            for (int gi = 0; gi < 2; ++gi) {
                int col = (gi ? t1 : t0) * 16 + lm;
                float bias = b_ih[col] + b_hh[col];
#pragma unroll
                for (int mt = 0; mt < 4; ++mt)
                    acc[mt * 2 + gi] = (f32x4){bias, bias, bias, bias};
            }
            gemm_pass(acc, lds_hx, Wih_s, t0, t1, lm, lg, l);
#pragma unroll
            for (int f = 0; f < 8; ++f) {
                half4v xv;
#pragma unroll
                for (int r = 0; r < 4; ++r) xv[r] = (half_t)acc[f][r];
                *reinterpret_cast<half4v*>(
                    &lds_xp[((w * 16 + pass * 8 + f) * 64 + l) * 4]) = xv;
            }
        }
    }
    __syncthreads();   // x tile fully consumed, xp written

    // ---- stage h0 into lds_hx (coalesced on c); cx into registers ----
    {
        const float* hin = hx0 + (size_t)row0 * 256;
        for (int it = 0; it < 16; ++it) {
            int idx = it * 1024 + tid;
            int c = idx & 255, p = idx >> 8;
            lds_hx[p * 256 + (c ^ ((p & 7) << 4))] = (half_t)hin[p * 256 + c];
        }
    }
    float cxr[16];
#pragma unroll
    for (int mt = 0; mt < 4; ++mt)
#pragma unroll
        for (int r = 0; r < 4; ++r) {
            int p = mt * 16 + lg * 4 + r;
            cxr[mt * 4 + r] = cx0[(size_t)(row0 + p) * 256 + w * 16 + lm];
        }
    __syncthreads();

    // ---------------- 16 recurrent steps ----------------
#pragma unroll 1
    for (int t = 0; t < 16; ++t) {
        f32x4 acc[8];
        float p1[16];

        // ---- pass A: gates i,g ----
#pragma unroll
        for (int f = 0; f < 8; ++f) {
            half4v u = *reinterpret_cast<const half4v*>(
                &lds_xp[((w * 16 + f) * 64 + l) * 4]);
#pragma unroll
            for (int r = 0; r < 4; ++r) acc[f][r] = (float)u[r];
        }
        gemm_pass(acc, lds_hx, Whh_s, tA0, tA1, lm, lg, l);
#pragma unroll
        for (int mt = 0; mt < 4; ++mt)
#pragma unroll
            for (int r = 0; r < 4; ++r)
                p1[mt * 4 + r] = fast_sigmoid(acc[mt * 2 + 0][r]) *
                                 fast_tanh(acc[mt * 2 + 1][r]);
        __builtin_amdgcn_sched_barrier(0);

        // ---- pass B: gates f,o ----
#pragma unroll
        for (int f = 0; f < 8; ++f) {
            half4v u = *reinterpret_cast<const half4v*>(
                &lds_xp[((w * 16 + 8 + f) * 64 + l) * 4]);
#pragma unroll
            for (int r = 0; r < 4; ++r) acc[f][r] = (float)u[r];
        }
        gemm_pass(acc, lds_hx, Whh_s, tB0, tB1, lm, lg, l);

        __syncthreads();   // all waves finished reading lds_hx(t)

        // cell update; write hx(t+1) into lds_hx (f16, swizzled)
#pragma unroll
        for (int mt = 0; mt < 4; ++mt)
#pragma unroll
            for (int r = 0; r < 4; ++r) {
                float sf = fast_sigmoid(acc[mt * 2 + 0][r]);
                float so = fast_sigmoid(acc[mt * 2 + 1][r]);
                float cxn = sf * cxr[mt * 4 + r] + p1[mt * 4 + r];
                cxr[mt * 4 + r] = cxn;
                float h = so * fast_tanh(cxn);
                int p = mt * 16 + lg * 4 + r;
                lds_hx[p * 256 + ((w * 16 + lm) ^ ((p & 7) << 4))] = (half_t)h;
            }
        __syncthreads();   // hx(t+1) visible to all

        // head: y = leaky_relu(hx) @ W_lin^T + b_lin, write [n][t][o]
        {
            const int p = tid >> 4;          // row 0..63
            const int o = (tid >> 3) & 1;    // output 0..1
            const int q = tid & 7;           // eighth of the 256 h-cols
            const float* wl = W_lin + o * 256;
            float s = 0.0f;
#pragma unroll
            for (int cb = 0; cb < 8; ++cb) {
                int c0 = q * 32 + cb * 4;
                half4v u = *reinterpret_cast<const half4v*>(
                    &lds_hx[p * 256 + (c0 ^ ((p & 7) << 4))]);
                float4 wv = *reinterpret_cast<const float4*>(wl + c0);
                float h0 = (float)u[0], h1 = (float)u[1];
                float h2 = (float)u[2], h3 = (float)u[3];
                s += fmaxf(h0, 0.01f * h0) * wv.x;
                s += fmaxf(h1, 0.01f * h1) * wv.y;
                s += fmaxf(h2, 0.01f * h2) * wv.z;
                s += fmaxf(h3, 0.01f * h3) * wv.w;
            }
            s += __shfl_xor(s, 1);
            s += __shfl_xor(s, 2);
            s += __shfl_xor(s, 4);
            if (q == 0)
                out[((size_t)(row0 + p) * 16 + t) * 2 + o] = s + b_lin[o];
        }
    }
}

// ---------------------------------------------------------------------------
extern "C" void kernel_launch(void* const* d_in, const int* in_sizes, int n_in,
                              void* d_out, int out_size, void* d_ws, size_t ws_size,
                              hipStream_t stream)
{
    const float* x    = (const float*)d_in[0];
    const float* hx   = (const float*)d_in[1];
    const float* cx   = (const float*)d_in[2];
    const float* Wih  = (const float*)d_in[3];
    const float* Whh  = (const float*)d_in[4];
    const float* bih  = (const float*)d_in[5];
    const float* bhh  = (const float*)d_in[6];
    const float* Wlin = (const float*)d_in[7];
    const float* blin = (const float*)d_in[8];
    float* out = (float*)d_out;

    half_t* wih_s = (half_t*)d_ws;             // 512 KB
    half_t* whh_s = wih_s + 1024 * 256;        // 512 KB

    shuffle_w_kernel<<<512, 64, 0, stream>>>(Wih, wih_s);
    shuffle_w_kernel<<<512, 64, 0, stream>>>(Whh, whh_s);
    lstm_kernel<<<200, 1024, 0, stream>>>(x, hx, cx, bih, bhh, Wlin, blin,
                                          wih_s, whh_s, out);
}